// Round 3
// baseline (468.470 us; speedup 1.0000x reference)
//
#include <hip/hip_runtime.h>
#include <hip/hip_bf16.h>

// Problem constants
constexpr int BB   = 16;
constexpr int TT_  = 392;          // T
constexpr int CC   = 512;          // C (= E)
constexpr int E8_  = 64;           // E/8
constexpr int KK   = 196;          // top_k
constexpr long TT2 = 153664;       // T*T
constexpr long OUT_HALF = 1229312; // B*T*K

// fused att+xt tiling: 98 chunks (4 att i-rows each) x 7 j-blocks of 64 j.
constexpr int NC2 = 98;            // K-chunks (c); chunk c covers i in [4c, 4c+4)
constexpr int CH2 = 1568;          // flattened K per chunk (4 * 392)
// P LDS row stride (bf16 elems): 790 dwords == 2 mod 4 -> 16 n-lanes hit
// 16 distinct banks on the 8B fragment reads (2-way = free), as proven by LDA/LDW.
constexpr int LDP = 1580;

typedef __bf16 bf16_t;
typedef bf16_t bf16x8 __attribute__((ext_vector_type(8)));
typedef float  f32x4  __attribute__((ext_vector_type(4)));

static __device__ __forceinline__ unsigned int pk2(float a, float b) {
    unsigned short lo = __builtin_bit_cast(unsigned short, (bf16_t)a);
    unsigned short hi = __builtin_bit_cast(unsigned short, (bf16_t)b);
    return ((unsigned int)hi << 16) | (unsigned int)lo;
}
static __device__ __forceinline__ bf16x8 cvt8(f32x4 a, f32x4 b) {
    uint4 u = make_uint4(pk2(a.x, a.y), pk2(a.z, a.w), pk2(b.x, b.y), pk2(b.z, b.w));
    return __builtin_bit_cast(bf16x8, u);
}
// 8B-aligned LDS fragment load
static __device__ __forceinline__ bf16x8 ld_frag(const bf16_t* p) {
    uint2 lo = *(const uint2*)p;
    uint2 hi = *(const uint2*)(p + 4);
    uint4 u = make_uint4(lo.x, lo.y, hi.x, hi.y);
    return __builtin_bit_cast(bf16x8, u);
}

// ---------------------------------------------------------------- xi = bf16(x @ W_dim^T + b_dim)
// LDS-free: every x row feeds one wave; W_dim (131 KB) is L2-hot across the 98 blocks.
// Per wave: 16 m-rows x 64 e, K=512 in 16 steps, 2-deep register pipeline.
// Also zero-inits xt (ws is poisoned every call).
__global__ __launch_bounds__(256) void k_xi(const float* __restrict__ x,
                                            const float* __restrict__ Wd,
                                            const float* __restrict__ bd,
                                            unsigned short* __restrict__ xi_b,
                                            float* __restrict__ xt) {
    int tid = threadIdx.x;
    if (blockIdx.x < 25) {
        int o = blockIdx.x * 256 + tid;
        if (o < BB * TT_) xt[o] = 0.f;
    }
    int wv = tid >> 6, lane = tid & 63;
    int n = lane & 15, quad = lane >> 4;
    int m = blockIdx.x * 64 + wv * 16 + n;          // 98*64 = 6272 = B*T exactly
    const float* xp = x  + (size_t)m * CC + quad * 8;
    const float* wp = Wd + (size_t)n * CC + quad * 8;   // + nt*16*CC for e-row

    f32x4 acc[4] = {};
    f32x4 a0c, a1c, b0c[4], b1c[4];
    a0c = *(const f32x4*)xp;
    a1c = *(const f32x4*)(xp + 4);
    #pragma unroll
    for (int nt = 0; nt < 4; ++nt) {
        b0c[nt] = *(const f32x4*)(wp + (size_t)nt * 16 * CC);
        b1c[nt] = *(const f32x4*)(wp + (size_t)nt * 16 * CC + 4);
    }
    for (int kt = 0; kt < 16; ++kt) {
        f32x4 a0n, a1n, b0n[4], b1n[4];
        if (kt < 15) {
            a0n = *(const f32x4*)(xp + (kt + 1) * 32);
            a1n = *(const f32x4*)(xp + (kt + 1) * 32 + 4);
            #pragma unroll
            for (int nt = 0; nt < 4; ++nt) {
                b0n[nt] = *(const f32x4*)(wp + (size_t)nt * 16 * CC + (kt + 1) * 32);
                b1n[nt] = *(const f32x4*)(wp + (size_t)nt * 16 * CC + (kt + 1) * 32 + 4);
            }
        }
        bf16x8 a = cvt8(a0c, a1c);
        #pragma unroll
        for (int nt = 0; nt < 4; ++nt) {
            bf16x8 b = cvt8(b0c[nt], b1c[nt]);
            acc[nt] = __builtin_amdgcn_mfma_f32_16x16x32_bf16(a, b, acc[nt], 0, 0, 0);
        }
        if (kt < 15) {
            a0c = a0n; a1c = a1n;
            #pragma unroll
            for (int nt = 0; nt < 4; ++nt) { b0c[nt] = b0n[nt]; b1c[nt] = b1n[nt]; }
        }
    }
    #pragma unroll
    for (int nt = 0; nt < 4; ++nt)
        #pragma unroll
        for (int r = 0; r < 4; ++r) {
            int mm = blockIdx.x * 64 + wv * 16 + quad * 4 + r;
            int e = nt * 16 + n;
            xi_b[(size_t)mm * E8_ + e] =
                __builtin_bit_cast(unsigned short, (bf16_t)(acc[nt][r] + bd[e]));
        }
}

// ---------------------------------------------------------------- fused att+xt
// Chunk c consumes att rows i in [4c,4c+4) ONLY -> att never materialized.
// grid 728 = 8 xcd * 13 cidx * 7 jb, block 256 (4 waves). All 7 j-blocks of a
// chunk pin to one XCD (L2 reuse of xi_b / W locality).
// Phase 1: each wave computes scores+softmax for 4 batches (A rows = 4 i's,
//   B = full xi[b], straight from L2-hot global), parks P bf16 in LDS [b][i_l*392+k].
// Phase 2: proven register-streamed W_time MFMA, A-fragments from LDS P.
__global__ __launch_bounds__(256) void k_attxt(const float* __restrict__ Wt,
                                               const unsigned short* __restrict__ xi_b,
                                               float* __restrict__ xt) {
    __shared__ bf16_t P[16 * LDP];          // 50,560 B
    int wg = blockIdx.x;
    int xcd = wg & 7, s = wg >> 3;          // s = 0..90
    int cidx = s / 7, jb = s - cidx * 7;
    int c = cidx * 8 + xcd;
    if (c >= NC2) return;                   // 42 idle blocks (whole block exits: no barrier hazard)
    int tid = threadIdx.x;
    int wv = tid >> 6, lane = tid & 63;
    int n = lane & 15, quad = lane >> 4;

    // phase-2 pointers; prefetch first W step early (independent of phase 1)
    int j = jb * 64 + wv * 16 + n;
    int jl = j < TT_ ? j : TT_ - 1;         // clamp row for loads; store guarded
    long kbase = (long)c * CH2;
    const float* wp = Wt + (size_t)jl * TT2 + kbase + quad * 8;
    f32x4 w0c = *(const f32x4*)wp;
    f32x4 w1c = *(const f32x4*)(wp + 4);

    // ---------------- phase 1: scores + softmax -> P
    const float scaler = 1.0f / 512.0f;
    for (int bb = 0; bb < 4; ++bb) {
        int b = wv * 4 + bb;
        const unsigned short* xb = xi_b + (size_t)b * TT_ * E8_;
        // A rows: n<4 -> xi[b, 4c+n]; clamp others (rows 4..15 of D are discarded)
        int ar = 4 * c + (n < 4 ? n : 3);
        uint4 av0 = *(const uint4*)(xb + (size_t)ar * E8_ + quad * 8);
        uint4 av1 = *(const uint4*)(xb + (size_t)ar * E8_ + 32 + quad * 8);
        bf16x8 a0 = __builtin_bit_cast(bf16x8, av0);
        bf16x8 a1 = __builtin_bit_cast(bf16x8, av1);
        f32x4 acc[25];
        #pragma unroll
        for (int nt = 0; nt < 25; ++nt) acc[nt] = (f32x4){0.f, 0.f, 0.f, 0.f};
        #pragma unroll
        for (int nt = 0; nt < 25; ++nt) {
            int tj = nt * 16 + n;
            int tjl = tj < TT_ ? tj : TT_ - 1;   // dup rows masked below (same as old zero-pad+mask)
            uint4 bv0 = *(const uint4*)(xb + (size_t)tjl * E8_ + quad * 8);
            uint4 bv1 = *(const uint4*)(xb + (size_t)tjl * E8_ + 32 + quad * 8);
            acc[nt] = __builtin_amdgcn_mfma_f32_16x16x32_bf16(
                a0, __builtin_bit_cast(bf16x8, bv0), acc[nt], 0, 0, 0);
            acc[nt] = __builtin_amdgcn_mfma_f32_16x16x32_bf16(
                a1, __builtin_bit_cast(bf16x8, bv1), acc[nt], 0, 0, 0);
        }
        // softmax over tj (rows i = 4c + (quad*4+r); only quad 0 rows are real)
        float mx[4] = {-1e30f, -1e30f, -1e30f, -1e30f};
        #pragma unroll
        for (int nt = 0; nt < 25; ++nt) {
            bool valid = (nt * 16 + n) < TT_;
            #pragma unroll
            for (int r = 0; r < 4; ++r) {
                float v = valid ? acc[nt][r] * scaler : -1e30f;
                acc[nt][r] = v;
                mx[r] = fmaxf(mx[r], v);
            }
        }
        #pragma unroll
        for (int r = 0; r < 4; ++r) {
            #pragma unroll
            for (int o = 1; o < 16; o <<= 1) mx[r] = fmaxf(mx[r], __shfl_xor(mx[r], o, 64));
        }
        float sm[4] = {0.f, 0.f, 0.f, 0.f};
        #pragma unroll
        for (int nt = 0; nt < 25; ++nt)
            #pragma unroll
            for (int r = 0; r < 4; ++r) {
                float e = __expf(acc[nt][r] - mx[r]);
                acc[nt][r] = e;
                sm[r] += e;
            }
        #pragma unroll
        for (int r = 0; r < 4; ++r) {
            #pragma unroll
            for (int o = 1; o < 16; o <<= 1) sm[r] += __shfl_xor(sm[r], o, 64);
            sm[r] = 1.0f / sm[r];
        }
        if (quad == 0) {                     // rows 0..3 = i_local
            #pragma unroll
            for (int r = 0; r < 4; ++r)
                #pragma unroll
                for (int nt = 0; nt < 25; ++nt) {
                    int tj = nt * 16 + n;
                    if (tj < TT_)
                        P[b * LDP + r * TT_ + tj] = (bf16_t)(acc[nt][r] * sm[r]);
                }
        }
    }
    __syncthreads();

    // ---------------- phase 2: stream W_time, MFMA vs P (A row = b = n-lane)
    const bf16_t* pp = &P[n * LDP + quad * 8];
    f32x4 acc2 = {0.f, 0.f, 0.f, 0.f};
    for (int m = 0; m < 49; ++m) {          // K = 49*32, same order as split version
        f32x4 w0n, w1n;
        if (m < 48) {
            w0n = *(const f32x4*)(wp + (m + 1) * 32);
            w1n = *(const f32x4*)(wp + (m + 1) * 32 + 4);
        }
        bf16x8 a = ld_frag(pp + m * 32);
        bf16x8 b = cvt8(w0c, w1c);
        acc2 = __builtin_amdgcn_mfma_f32_16x16x32_bf16(a, b, acc2, 0, 0, 0);
        if (m < 48) { w0c = w0n; w1c = w1n; }
    }
    if (j < TT_) {
        #pragma unroll
        for (int r = 0; r < 4; ++r)
            unsafeAtomicAdd(&xt[(size_t)(quad * 4 + r) * TT_ + j], acc2[r]);
    }
}

// ---------------------------------------------------------------- offsets -> unnormalized sample coord ix
__global__ __launch_bounds__(256) void k_off(const float* __restrict__ xt,
                                             const float* __restrict__ bt,
                                             const float* __restrict__ Wa,
                                             const float* __restrict__ Wd,
                                             float* __restrict__ wix) {
    int o = blockIdx.x * 256 + threadIdx.x;
    if (o >= 2 * BB * KK) return;                  // 6272
    int which = o / (BB * KK);                     // 0 = a, 1 = d
    int rem = o - which * (BB * KK);
    int b = rem / KK;
    int k = rem - b * KK;
    const f32x4* __restrict__ wr = (const f32x4*)((which ? Wd : Wa) + (size_t)k * TT_);
    const f32x4* __restrict__ xr = (const f32x4*)(xt + (size_t)b * TT_);
    const f32x4* __restrict__ br = (const f32x4*)bt;
    float acc = 0.f;
    #pragma unroll 2
    for (int q = 0; q < TT_ / 4; ++q) {
        f32x4 w = wr[q], x = xr[q], bb = br[q];
        acc += (x.x + bb.x) * w.x + (x.y + bb.y) * w.y
             + (x.z + bb.z) * w.z + (x.w + bb.w) * w.w;
    }
    float off = tanhf(acc) * 2.0f;                 // * RECEPTIVE_FIELD
    float idx = (float)(2 * k + which) + off;      // arange(0,t,2) or arange(1,t+1,2)
    float g = 2.0f * idx / 391.0f - 1.0f;          // normalize_grid, denom = t-1
    float ix = ((g + 1.0f) * 512.0f - 1.0f) * 0.5f; // grid_sample unnormalize, c=512
    wix[o] = ix;
}

// ---------------------------------------------------------------- bilinear gather along channels
__global__ __launch_bounds__(256) void k_sample(const float* __restrict__ x,
                                                const float* __restrict__ wix,
                                                float* __restrict__ out) {
    __shared__ float xr[4][512];
    int b = blockIdx.x, t0 = blockIdx.y * 4;
    int tid = threadIdx.x;
    const float* src = x + ((size_t)b * TT_ + t0) * CC;
    #pragma unroll
    for (int s = 0; s < 2; ++s) {
        int idx = s * 256 + tid;                   // 0..511 float4 slots
        ((f32x4*)xr)[idx] = ((const f32x4*)src)[idx];
    }
    __syncthreads();
    for (int w = tid; w < 2 * 4 * KK; w += 256) {  // 1568 items
        int which = (w >= 4 * KK) ? 1 : 0;
        int rem = w - which * 4 * KK;
        int tl = rem / KK;
        int k = rem - tl * KK;
        float ix = wix[(size_t)which * (BB * KK) + b * KK + k];
        float x0f = floorf(ix);
        float w1 = ix - x0f;
        int c0 = (int)x0f;
        int c1 = c0 + 1;
        c0 = min(max(c0, 0), CC - 1);
        c1 = min(max(c1, 0), CC - 1);
        float v0 = xr[tl][c0], v1 = xr[tl][c1];
        out[(size_t)which * OUT_HALF + ((size_t)(b * TT_) + t0 + tl) * KK + k] =
            v0 * (1.0f - w1) + v1 * w1;
    }
}

extern "C" void kernel_launch(void* const* d_in, const int* in_sizes, int n_in,
                              void* d_out, int out_size, void* d_ws, size_t ws_size,
                              hipStream_t stream) {
    const float* x_in   = (const float*)d_in[0];
    const float* W_dim  = (const float*)d_in[1];
    const float* b_dim  = (const float*)d_in[2];
    const float* W_time = (const float*)d_in[3];
    const float* b_time = (const float*)d_in[4];
    const float* W_offa = (const float*)d_in[5];
    const float* W_offd = (const float*)d_in[6];
    float* out = (float*)d_out;
    float* ws  = (float*)d_ws;

    // ws layout (float units): att buffer no longer exists.
    unsigned short* xi_b = (unsigned short*)ws;   // 6272*64 bf16 = 200,704 fl
    float*          xt   = ws + 200704;           // 6,272 fl (zeroed by k_xi)
    float*          wix  = ws + 206976;           // 6,272 fl

    k_xi<<<98, 256, 0, stream>>>(x_in, W_dim, b_dim, xi_b, xt);
    k_attxt<<<728, 256, 0, stream>>>(W_time, xi_b, xt);
    k_off<<<25, 256, 0, stream>>>(xt, b_time, W_offa, W_offd, wix);
    k_sample<<<dim3(BB, TT_ / 4), 256, 0, stream>>>(x_in, wix, out);
}

// Round 4
// 418.174 us; speedup vs baseline: 1.1203x; 1.1203x over previous
//
#include <hip/hip_runtime.h>
#include <hip/hip_bf16.h>

// Problem constants
constexpr int BB   = 16;
constexpr int TT_  = 392;          // T
constexpr int CC   = 512;          // C (= E)
constexpr int E8_  = 64;           // E/8
constexpr int KK   = 196;          // top_k
constexpr long TT2 = 153664;       // T*T
constexpr long OUT_HALF = 1229312; // B*T*K

// k_xt K-split tiling: flattened K = T*T = 4802*32. 343 chunks x 448 elems (14 MFMA
// steps). Waves = 343 chunks x 25 j-tiles = 8575 (~33/CU) -> latency fully hidden by
// TLP (R3 post-mortem: 2450 waves = 9.6/CU was latency-bound at 9% HBM, 16% occ).
constexpr int NCH = 343;           // K-chunks
constexpr int KCH = 448;           // K elems per chunk
constexpr int NST = 14;            // MFMA steps per chunk (KCH/32)

// k_att LDS stride (rows 8-mod-16 aligned: dword-stride 2 mod 4 -> 2-way free)
constexpr int LDA = 68;

typedef __bf16 bf16_t;
typedef bf16_t bf16x8 __attribute__((ext_vector_type(8)));
typedef float  f32x4  __attribute__((ext_vector_type(4)));

static __device__ __forceinline__ unsigned int pk2(float a, float b) {
    unsigned short lo = __builtin_bit_cast(unsigned short, (bf16_t)a);
    unsigned short hi = __builtin_bit_cast(unsigned short, (bf16_t)b);
    return ((unsigned int)hi << 16) | (unsigned int)lo;
}
static __device__ __forceinline__ bf16x8 cvt8(f32x4 a, f32x4 b) {
    uint4 u = make_uint4(pk2(a.x, a.y), pk2(a.z, a.w), pk2(b.x, b.y), pk2(b.z, b.w));
    return __builtin_bit_cast(bf16x8, u);
}
// 8B-aligned LDS fragment load
static __device__ __forceinline__ bf16x8 ld_frag(const bf16_t* p) {
    uint2 lo = *(const uint2*)p;
    uint2 hi = *(const uint2*)(p + 4);
    uint4 u = make_uint4(lo.x, lo.y, hi.x, hi.y);
    return __builtin_bit_cast(bf16x8, u);
}

// ---------------------------------------------------------------- xi = bf16(x @ W_dim^T + b_dim)
// LDS-free: every x row feeds one wave; W_dim (131 KB) is L2-hot across the 98 blocks.
// Per wave: 16 m-rows x 64 e, K=512 in 16 steps, 2-deep register pipeline.
// Also zero-inits xt (ws is poisoned every call).
__global__ __launch_bounds__(256) void k_xi(const float* __restrict__ x,
                                            const float* __restrict__ Wd,
                                            const float* __restrict__ bd,
                                            unsigned short* __restrict__ xi_b,
                                            float* __restrict__ xt) {
    int tid = threadIdx.x;
    if (blockIdx.x < 25) {
        int o = blockIdx.x * 256 + tid;
        if (o < BB * TT_) xt[o] = 0.f;
    }
    int wv = tid >> 6, lane = tid & 63;
    int n = lane & 15, quad = lane >> 4;
    int m = blockIdx.x * 64 + wv * 16 + n;          // 98*64 = 6272 = B*T exactly
    const float* xp = x  + (size_t)m * CC + quad * 8;
    const float* wp = Wd + (size_t)n * CC + quad * 8;   // + nt*16*CC for e-row

    f32x4 acc[4] = {};
    f32x4 a0c, a1c, b0c[4], b1c[4];
    a0c = *(const f32x4*)xp;
    a1c = *(const f32x4*)(xp + 4);
    #pragma unroll
    for (int nt = 0; nt < 4; ++nt) {
        b0c[nt] = *(const f32x4*)(wp + (size_t)nt * 16 * CC);
        b1c[nt] = *(const f32x4*)(wp + (size_t)nt * 16 * CC + 4);
    }
    for (int kt = 0; kt < 16; ++kt) {
        f32x4 a0n, a1n, b0n[4], b1n[4];
        if (kt < 15) {
            a0n = *(const f32x4*)(xp + (kt + 1) * 32);
            a1n = *(const f32x4*)(xp + (kt + 1) * 32 + 4);
            #pragma unroll
            for (int nt = 0; nt < 4; ++nt) {
                b0n[nt] = *(const f32x4*)(wp + (size_t)nt * 16 * CC + (kt + 1) * 32);
                b1n[nt] = *(const f32x4*)(wp + (size_t)nt * 16 * CC + (kt + 1) * 32 + 4);
            }
        }
        bf16x8 a = cvt8(a0c, a1c);
        #pragma unroll
        for (int nt = 0; nt < 4; ++nt) {
            bf16x8 b = cvt8(b0c[nt], b1c[nt]);
            acc[nt] = __builtin_amdgcn_mfma_f32_16x16x32_bf16(a, b, acc[nt], 0, 0, 0);
        }
        if (kt < 15) {
            a0c = a0n; a1c = a1n;
            #pragma unroll
            for (int nt = 0; nt < 4; ++nt) { b0c[nt] = b0n[nt]; b1c[nt] = b1n[nt]; }
        }
    }
    #pragma unroll
    for (int nt = 0; nt < 4; ++nt)
        #pragma unroll
        for (int r = 0; r < 4; ++r) {
            int mm = blockIdx.x * 64 + wv * 16 + quad * 4 + r;
            int e = nt * 16 + n;
            xi_b[(size_t)mm * E8_ + e] =
                __builtin_bit_cast(unsigned short, (bf16_t)(acc[nt][r] + bd[e]));
        }
}

// ---------------------------------------------------------------- fused scores + softmax -> att bf16
// grid (16 b, 7 ti-tiles), block 256 (4 waves). Wave: 16 ti x full 392 tj (25 n-tiles).
__global__ __launch_bounds__(256) void k_att(const unsigned short* __restrict__ xi_b,
                                             unsigned short* __restrict__ att_b) {
    __shared__ bf16_t Xb[400 * LDA];
    int b = blockIdx.x, tb = blockIdx.y;
    int tid = threadIdx.x;
    int wv = tid >> 6, lane = tid & 63;
    int n = lane & 15, quad = lane >> 4;
    #pragma unroll
    for (int t = 0; t < 13; ++t) {
        int s = t * 256 + tid;              // 0..3327, guard 3200
        if (s < 3200) {
            int r = s >> 3, c8 = s & 7;
            uint2 lo = make_uint2(0u, 0u), hi = make_uint2(0u, 0u);
            if (r < TT_) {
                uint4 v = *(const uint4*)(xi_b + ((size_t)(b * TT_ + r)) * E8_ + c8 * 8);
                lo = make_uint2(v.x, v.y);
                hi = make_uint2(v.z, v.w);
            }
            *(uint2*)(&Xb[r * LDA + c8 * 8])     = lo;
            *(uint2*)(&Xb[r * LDA + c8 * 8 + 4]) = hi;
        }
    }
    __syncthreads();
    int arow = tb * 64 + wv * 16 + n;
    if (arow > 399) arow = 399;
    bf16x8 a0 = ld_frag(&Xb[arow * LDA + quad * 8]);
    bf16x8 a1 = ld_frag(&Xb[arow * LDA + 32 + quad * 8]);
    f32x4 acc[25];
    #pragma unroll
    for (int nt = 0; nt < 25; ++nt) acc[nt] = (f32x4){0.f, 0.f, 0.f, 0.f};
    #pragma unroll
    for (int nt = 0; nt < 25; ++nt) {
        bf16x8 b0 = ld_frag(&Xb[(nt * 16 + n) * LDA + quad * 8]);
        bf16x8 b1 = ld_frag(&Xb[(nt * 16 + n) * LDA + 32 + quad * 8]);
        acc[nt] = __builtin_amdgcn_mfma_f32_16x16x32_bf16(a0, b0, acc[nt], 0, 0, 0);
        acc[nt] = __builtin_amdgcn_mfma_f32_16x16x32_bf16(a1, b1, acc[nt], 0, 0, 0);
    }
    const float scaler = 1.0f / 512.0f;
    float mx[4] = {-1e30f, -1e30f, -1e30f, -1e30f};
    #pragma unroll
    for (int nt = 0; nt < 25; ++nt) {
        bool valid = (nt * 16 + n) < TT_;
        #pragma unroll
        for (int r = 0; r < 4; ++r) {
            float v = valid ? acc[nt][r] * scaler : -1e30f;
            acc[nt][r] = v;
            mx[r] = fmaxf(mx[r], v);
        }
    }
    #pragma unroll
    for (int r = 0; r < 4; ++r) {
        #pragma unroll
        for (int o = 1; o < 16; o <<= 1) mx[r] = fmaxf(mx[r], __shfl_xor(mx[r], o, 64));
    }
    float sm[4] = {0.f, 0.f, 0.f, 0.f};
    #pragma unroll
    for (int nt = 0; nt < 25; ++nt)
        #pragma unroll
        for (int r = 0; r < 4; ++r) {
            float e = __expf(acc[nt][r] - mx[r]);
            acc[nt][r] = e;
            sm[r] += e;
        }
    #pragma unroll
    for (int r = 0; r < 4; ++r) {
        #pragma unroll
        for (int o = 1; o < 16; o <<= 1) sm[r] += __shfl_xor(sm[r], o, 64);
        sm[r] = 1.0f / sm[r];
    }
    unsigned short* dst = att_b + (size_t)b * TT2;
    #pragma unroll
    for (int r = 0; r < 4; ++r) {
        int ti = tb * 64 + wv * 16 + quad * 4 + r;
        if (ti < TT_) {
            #pragma unroll
            for (int nt = 0; nt < 25; ++nt) {
                int tj = nt * 16 + n;
                if (tj < TT_)
                    dst[(size_t)ti * TT_ + tj] =
                        __builtin_bit_cast(unsigned short, (bf16_t)(acc[nt][r] * sm[r]));
            }
        }
    }
}

// ---------------------------------------------------------------- xt via MFMA + fp32 atomic accumulate
// LDS-free, K-split streaming. grid (343 c, 7 jb), block 256 (4 waves, wave = 16 j).
// Per wave: A = att[b=0..15, K-slice] (bf16, 16B/lane), B = W_time rows (2x f32x4/lane,
// coalesced), 14 MFMA steps, 2-deep register pipeline, 4 atomics/lane into fp32 xt.
// 8575 active waves (~33/CU) -> global-load latency hidden by TLP, not pipeline depth.
__global__ __launch_bounds__(256) void k_xt(const float* __restrict__ Wt,
                                            const unsigned short* __restrict__ att_b,
                                            float* __restrict__ xt) {
    int c = blockIdx.x;                     // K-slice [c*KCH, (c+1)*KCH)
    int jb = blockIdx.y;                    // 0..6
    int tid = threadIdx.x;
    int wv = tid >> 6, lane = tid & 63;
    int n = lane & 15, quad = lane >> 4;
    int jt = jb * 4 + wv;
    if (jt >= 25) return;                   // 3 idle waves on jb == 6 (no barriers -> safe)
    int j = jt * 16 + n;
    int jl = j < TT_ ? j : TT_ - 1;         // clamp W row (store guarded)
    long kbase = (long)c * KCH;
    const unsigned short* ap = att_b + (size_t)n * TT2 + kbase + quad * 8;
    const float*          wp = Wt + (size_t)jl * TT2 + kbase + quad * 8;

    f32x4 acc = {0.f, 0.f, 0.f, 0.f};
    uint4 ac  = *(const uint4*)ap;
    f32x4 w0c = *(const f32x4*)wp;
    f32x4 w1c = *(const f32x4*)(wp + 4);
    for (int m = 0; m < NST; ++m) {
        uint4 an; f32x4 w0n, w1n;
        if (m < NST - 1) {
            an  = *(const uint4*)(ap + (m + 1) * 32);
            w0n = *(const f32x4*)(wp + (m + 1) * 32);
            w1n = *(const f32x4*)(wp + (m + 1) * 32 + 4);
        }
        acc = __builtin_amdgcn_mfma_f32_16x16x32_bf16(
            __builtin_bit_cast(bf16x8, ac), cvt8(w0c, w1c), acc, 0, 0, 0);
        if (m < NST - 1) { ac = an; w0c = w0n; w1c = w1n; }
    }
    if (j < TT_) {
        #pragma unroll
        for (int r = 0; r < 4; ++r)
            unsafeAtomicAdd(&xt[(size_t)(quad * 4 + r) * TT_ + j], acc[r]);
    }
}

// ---------------------------------------------------------------- offsets -> unnormalized sample coord ix
__global__ __launch_bounds__(256) void k_off(const float* __restrict__ xt,
                                             const float* __restrict__ bt,
                                             const float* __restrict__ Wa,
                                             const float* __restrict__ Wd,
                                             float* __restrict__ wix) {
    int o = blockIdx.x * 256 + threadIdx.x;
    if (o >= 2 * BB * KK) return;                  // 6272
    int which = o / (BB * KK);                     // 0 = a, 1 = d
    int rem = o - which * (BB * KK);
    int b = rem / KK;
    int k = rem - b * KK;
    const f32x4* __restrict__ wr = (const f32x4*)((which ? Wd : Wa) + (size_t)k * TT_);
    const f32x4* __restrict__ xr = (const f32x4*)(xt + (size_t)b * TT_);
    const f32x4* __restrict__ br = (const f32x4*)bt;
    float acc = 0.f;
    #pragma unroll 2
    for (int q = 0; q < TT_ / 4; ++q) {
        f32x4 w = wr[q], x = xr[q], bb = br[q];
        acc += (x.x + bb.x) * w.x + (x.y + bb.y) * w.y
             + (x.z + bb.z) * w.z + (x.w + bb.w) * w.w;
    }
    float off = tanhf(acc) * 2.0f;                 // * RECEPTIVE_FIELD
    float idx = (float)(2 * k + which) + off;      // arange(0,t,2) or arange(1,t+1,2)
    float g = 2.0f * idx / 391.0f - 1.0f;          // normalize_grid, denom = t-1
    float ix = ((g + 1.0f) * 512.0f - 1.0f) * 0.5f; // grid_sample unnormalize, c=512
    wix[o] = ix;
}

// ---------------------------------------------------------------- bilinear gather along channels
__global__ __launch_bounds__(256) void k_sample(const float* __restrict__ x,
                                                const float* __restrict__ wix,
                                                float* __restrict__ out) {
    __shared__ float xr[4][512];
    int b = blockIdx.x, t0 = blockIdx.y * 4;
    int tid = threadIdx.x;
    const float* src = x + ((size_t)b * TT_ + t0) * CC;
    #pragma unroll
    for (int s = 0; s < 2; ++s) {
        int idx = s * 256 + tid;                   // 0..511 float4 slots
        ((f32x4*)xr)[idx] = ((const f32x4*)src)[idx];
    }
    __syncthreads();
    for (int w = tid; w < 2 * 4 * KK; w += 256) {  // 1568 items
        int which = (w >= 4 * KK) ? 1 : 0;
        int rem = w - which * 4 * KK;
        int tl = rem / KK;
        int k = rem - tl * KK;
        float ix = wix[(size_t)which * (BB * KK) + b * KK + k];
        float x0f = floorf(ix);
        float w1 = ix - x0f;
        int c0 = (int)x0f;
        int c1 = c0 + 1;
        c0 = min(max(c0, 0), CC - 1);
        c1 = min(max(c1, 0), CC - 1);
        float v0 = xr[tl][c0], v1 = xr[tl][c1];
        out[(size_t)which * OUT_HALF + ((size_t)(b * TT_) + t0 + tl) * KK + k] =
            v0 * (1.0f - w1) + v1 * w1;
    }
}

extern "C" void kernel_launch(void* const* d_in, const int* in_sizes, int n_in,
                              void* d_out, int out_size, void* d_ws, size_t ws_size,
                              hipStream_t stream) {
    const float* x_in   = (const float*)d_in[0];
    const float* W_dim  = (const float*)d_in[1];
    const float* b_dim  = (const float*)d_in[2];
    const float* W_time = (const float*)d_in[3];
    const float* b_time = (const float*)d_in[4];
    const float* W_offa = (const float*)d_in[5];
    const float* W_offd = (const float*)d_in[6];
    float* out = (float*)d_out;
    float* ws  = (float*)d_ws;

    // ws layout (float units):
    unsigned short* att_b = (unsigned short*)ws;             // 16*153664 bf16
    unsigned short* xi_b  = (unsigned short*)(ws + 1229312); // 6272*64 bf16
    float*          xt    = ws + 1630720;                    // 6,272 fl (zeroed by k_xi)
    float*          wix   = ws + 1636992;                    // 6,272 fl

    k_xi<<<98, 256, 0, stream>>>(x_in, W_dim, b_dim, xi_b, xt);
    k_att<<<dim3(BB, 7), 256, 0, stream>>>(xi_b, att_b);
    k_xt<<<dim3(NCH, 7), 256, 0, stream>>>(W_time, att_b, xt);
    k_off<<<25, 256, 0, stream>>>(xt, b_time, W_offa, W_offd, wix);
    k_sample<<<dim3(BB, TT_ / 4), 256, 0, stream>>>(x_in, wix, out);
}

// Round 5
// 406.211 us; speedup vs baseline: 1.1533x; 1.0294x over previous
//
#include <hip/hip_runtime.h>
#include <hip/hip_bf16.h>

// Problem constants
constexpr int BB   = 16;
constexpr int TT_  = 392;          // T
constexpr int CC   = 512;          // C (= E)
constexpr int E8_  = 64;           // E/8
constexpr int KK   = 196;          // top_k
constexpr long TT2 = 153664;       // T*T
constexpr long OUT_HALF = 1229312; // B*T*K

// k_xt tiling
constexpr int NC2   = 98;          // K-chunks
constexpr int CH2   = 1568;        // K per chunk (NC2*CH2 = T*T)
constexpr int BK2   = 224;         // K per LDS stage
constexpr int NSTEP = 7;           // CH2/BK2
constexpr int NJT   = 13;          // j-tiles of 32 (13*32=416 >= 392)
// LDS row strides in bf16 elems. Chosen so byte-stride ≡ 8 (mod 16):
// dword-stride ≡ 2 (mod 4) -> 16 n-lanes hit 16 distinct banks (2-way = free).
constexpr int LDW = 228;           // k_xt rows (224 elems + pad)
constexpr int LDX = 36;            // k_xi rows (32 elems + pad)
constexpr int LDA = 68;            // k_att rows (64 elems + pad)

typedef __bf16 bf16_t;
typedef bf16_t bf16x8 __attribute__((ext_vector_type(8)));
typedef float  f32x4  __attribute__((ext_vector_type(4)));

static __device__ __forceinline__ unsigned int pk2(float a, float b) {
    unsigned short lo = __builtin_bit_cast(unsigned short, (bf16_t)a);
    unsigned short hi = __builtin_bit_cast(unsigned short, (bf16_t)b);
    return ((unsigned int)hi << 16) | (unsigned int)lo;
}
// 8B-aligned fragment load: two ds_read_b64 (rows are 8-mod-16 aligned by design)
static __device__ __forceinline__ bf16x8 ld_frag(const bf16_t* p) {
    uint2 lo = *(const uint2*)p;
    uint2 hi = *(const uint2*)(p + 4);
    uint4 u = make_uint4(lo.x, lo.y, hi.x, hi.y);
    return __builtin_bit_cast(bf16x8, u);
}

// ---------------------------------------------------------------- xi = bf16(x @ W_dim^T + b_dim)  (MFMA)
// grid 98, block 256 (4 waves). Block tile: 64 m-rows x 64 e. K=512 in 16 steps of 32.
// Pipelined: stage kt+1 loads issued into regs before kt's MFMAs; LDS ping-pong, 1 barrier/stage.
// Also zero-inits xt (ws is poisoned 0xAA every call).
__global__ __launch_bounds__(256) void k_xi(const float* __restrict__ x,
                                            const float* __restrict__ Wd,
                                            const float* __restrict__ bd,
                                            unsigned short* __restrict__ xi_b,
                                            float* __restrict__ xt) {
    __shared__ bf16_t Xl[2][64 * LDX];
    __shared__ bf16_t Wl[2][64 * LDX];
    int tid = threadIdx.x;
    if (blockIdx.x < 25) {
        int o = blockIdx.x * 256 + tid;
        if (o < BB * TT_) xt[o] = 0.f;
    }
    int m0 = blockIdx.x * 64;
    int wv = tid >> 6, lane = tid & 63;
    int n = lane & 15, quad = lane >> 4;

    // staging coords: s = t*256+tid -> r = t*32 + (tid>>3), c4 = tid&7
    int rr = tid >> 3, c4 = tid & 7;
    const float* xsrc = x  + (size_t)(m0 + rr) * CC + c4 * 4;
    const float* wsrc = Wd + (size_t)rr * CC + c4 * 4;
    int dst = rr * LDX + c4 * 4;

    f32x4 xv[2], wq[2];
    auto LOADS = [&](int kt) {
        #pragma unroll
        for (int t = 0; t < 2; ++t) {
            xv[t] = *(const f32x4*)(xsrc + (size_t)t * 32 * CC + kt * 32);
            wq[t] = *(const f32x4*)(wsrc + (size_t)t * 32 * CC + kt * 32);
        }
    };
    auto WRITE = [&](int p) {
        #pragma unroll
        for (int t = 0; t < 2; ++t) {
            *(uint2*)(&Xl[p][dst + t * 32 * LDX]) =
                make_uint2(pk2(xv[t].x, xv[t].y), pk2(xv[t].z, xv[t].w));
            *(uint2*)(&Wl[p][dst + t * 32 * LDX]) =
                make_uint2(pk2(wq[t].x, wq[t].y), pk2(wq[t].z, wq[t].w));
        }
    };

    f32x4 acc[4] = {};
    LOADS(0); WRITE(0); __syncthreads();
    int p = 0;
    for (int kt = 0; kt < 16; ++kt) {
        if (kt + 1 < 16) LOADS(kt + 1);
        bf16x8 a = ld_frag(&Xl[p][(wv * 16 + n) * LDX + quad * 8]);
        #pragma unroll
        for (int nt = 0; nt < 4; ++nt) {
            bf16x8 b = ld_frag(&Wl[p][(nt * 16 + n) * LDX + quad * 8]);
            acc[nt] = __builtin_amdgcn_mfma_f32_16x16x32_bf16(a, b, acc[nt], 0, 0, 0);
        }
        if (kt + 1 < 16) WRITE(p ^ 1);
        __syncthreads();
        p ^= 1;
    }
    #pragma unroll
    for (int nt = 0; nt < 4; ++nt)
        #pragma unroll
        for (int r = 0; r < 4; ++r) {
            int m = m0 + wv * 16 + quad * 4 + r;
            int e = nt * 16 + n;
            xi_b[(size_t)m * E8_ + e] =
                __builtin_bit_cast(unsigned short, (bf16_t)(acc[nt][r] + bd[e]));
        }
}

// ---------------------------------------------------------------- fused scores + softmax -> att bf16
// grid (16 b, 7 ti-tiles), block 256 (4 waves). Wave: 16 ti x full 392 tj (25 n-tiles).
// xi is already bf16 -> staging is a pure copy (half the traffic, no cvt VALU).
__global__ __launch_bounds__(256) void k_att(const unsigned short* __restrict__ xi_b,
                                             unsigned short* __restrict__ att_b) {
    __shared__ bf16_t Xb[400 * LDA];
    int b = blockIdx.x, tb = blockIdx.y;
    int tid = threadIdx.x;
    int wv = tid >> 6, lane = tid & 63;
    int n = lane & 15, quad = lane >> 4;
    // stage xi batch (392x64 bf16), rows 392..399 zero. 400*8 = 3200 uint4-of-8-elems slots.
    #pragma unroll
    for (int t = 0; t < 13; ++t) {
        int s = t * 256 + tid;              // 0..3327, guard 3200
        if (s < 3200) {
            int r = s >> 3, c8 = s & 7;
            uint2 lo = make_uint2(0u, 0u), hi = make_uint2(0u, 0u);
            if (r < TT_) {
                uint4 v = *(const uint4*)(xi_b + ((size_t)(b * TT_ + r)) * E8_ + c8 * 8);
                lo = make_uint2(v.x, v.y);
                hi = make_uint2(v.z, v.w);
            }
            *(uint2*)(&Xb[r * LDA + c8 * 8])     = lo;
            *(uint2*)(&Xb[r * LDA + c8 * 8 + 4]) = hi;
        }
    }
    __syncthreads();
    int arow = tb * 64 + wv * 16 + n;
    if (arow > 399) arow = 399;
    bf16x8 a0 = ld_frag(&Xb[arow * LDA + quad * 8]);        // k 0..31
    bf16x8 a1 = ld_frag(&Xb[arow * LDA + 32 + quad * 8]);   // k 32..63
    f32x4 acc[25];
    #pragma unroll
    for (int nt = 0; nt < 25; ++nt) acc[nt] = (f32x4){0.f, 0.f, 0.f, 0.f};
    #pragma unroll
    for (int nt = 0; nt < 25; ++nt) {
        bf16x8 b0 = ld_frag(&Xb[(nt * 16 + n) * LDA + quad * 8]);
        bf16x8 b1 = ld_frag(&Xb[(nt * 16 + n) * LDA + 32 + quad * 8]);
        acc[nt] = __builtin_amdgcn_mfma_f32_16x16x32_bf16(a0, b0, acc[nt], 0, 0, 0);
        acc[nt] = __builtin_amdgcn_mfma_f32_16x16x32_bf16(a1, b1, acc[nt], 0, 0, 0);
    }
    // per-lane rows ti = quad*4 + r (within wave tile); cols tj = nt*16 + n.
    const float scaler = 1.0f / 512.0f;
    float mx[4] = {-1e30f, -1e30f, -1e30f, -1e30f};
    #pragma unroll
    for (int nt = 0; nt < 25; ++nt) {
        bool valid = (nt * 16 + n) < TT_;
        #pragma unroll
        for (int r = 0; r < 4; ++r) {
            float v = valid ? acc[nt][r] * scaler : -1e30f;
            acc[nt][r] = v;
            mx[r] = fmaxf(mx[r], v);
        }
    }
    #pragma unroll
    for (int r = 0; r < 4; ++r) {
        #pragma unroll
        for (int o = 1; o < 16; o <<= 1) mx[r] = fmaxf(mx[r], __shfl_xor(mx[r], o, 64));
    }
    float sm[4] = {0.f, 0.f, 0.f, 0.f};
    #pragma unroll
    for (int nt = 0; nt < 25; ++nt)
        #pragma unroll
        for (int r = 0; r < 4; ++r) {
            float e = __expf(acc[nt][r] - mx[r]);
            acc[nt][r] = e;
            sm[r] += e;
        }
    #pragma unroll
    for (int r = 0; r < 4; ++r) {
        #pragma unroll
        for (int o = 1; o < 16; o <<= 1) sm[r] += __shfl_xor(sm[r], o, 64);
        sm[r] = 1.0f / sm[r];
    }
    unsigned short* dst = att_b + (size_t)b * TT2;
    #pragma unroll
    for (int r = 0; r < 4; ++r) {
        int ti = tb * 64 + wv * 16 + quad * 4 + r;
        if (ti < TT_) {
            #pragma unroll
            for (int nt = 0; nt < 25; ++nt) {
                int tj = nt * 16 + n;
                if (tj < TT_)
                    dst[(size_t)ti * TT_ + tj] =
                        __builtin_bit_cast(unsigned short, (bf16_t)(acc[nt][r] * sm[r]));
            }
        }
    }
}

// ---------------------------------------------------------------- xt via MFMA + fp32 atomic accumulate
// grid (98 chunks, 13 j-tiles), block 128 (2 waves). Tile: 16 b x 32 j, K = 1568 in 7 stages of 224.
// Pipelined: stage s+1 global loads issued into regs BEFORE stage s MFMAs; LDS ping-pong,
// one barrier per stage -> loads stay in flight across compute (T14 issue-early/write-late).
// Empirically the best k_xt variant of the session (R1: 404.8 us total); minimal atomics (615K).
__global__ __launch_bounds__(128) void k_xt(const float* __restrict__ Wt,
                                            const unsigned short* __restrict__ att_b,
                                            float* __restrict__ xt) {
    __shared__ bf16_t Wl[2][32 * LDW];     // 2 x 14592 B
    __shared__ bf16_t Al[2][16 * LDW];     // 2 x  7296 B   (total 43776 B -> 3 blocks/CU)
    int c = blockIdx.x, jt = blockIdx.y;
    int tid = threadIdx.x;
    int wv = tid >> 6, lane = tid & 63;
    int n = lane & 15, quad = lane >> 4;
    long kbase = (long)c * CH2;

    // W staging coords (14 f32x4 per thread per stage; 896B contiguous per row-chunk)
    const float* wsrc[14];
    int wdst[14];
    #pragma unroll
    for (int t = 0; t < 14; ++t) {
        int idx = t * 128 + tid;            // 0..1791
        int r = idx / 56, col = idx - r * 56;
        int jg = jt * 32 + r; if (jg > 391) jg = 391;
        wsrc[t] = Wt + (size_t)jg * TT2 + kbase + col * 4;
        wdst[t] = r * LDW + col * 4;
    }
    // att staging coords (already bf16; 16 rows x 28 x 16B per stage)
    const unsigned short* asrc[4];
    int adst[4];
    bool aok[4];
    #pragma unroll
    for (int t = 0; t < 4; ++t) {
        int idx = t * 128 + tid;            // 0..511, guard 448
        aok[t] = idx < 448;
        int r = aok[t] ? idx / 28 : 0;
        int q = aok[t] ? idx - r * 28 : 0;
        asrc[t] = att_b + (size_t)r * TT2 + kbase + q * 8;
        adst[t] = r * LDW + q * 8;
    }

    f32x4 wb[14];
    uint4 ab[4];
    auto LOADS = [&](int s) {
        long k0 = (long)s * BK2;
        #pragma unroll
        for (int t = 0; t < 14; ++t) wb[t] = *(const f32x4*)(wsrc[t] + k0);
        #pragma unroll
        for (int t = 0; t < 4; ++t) if (aok[t]) ab[t] = *(const uint4*)(asrc[t] + k0);
    };
    auto WRITE = [&](int p) {
        #pragma unroll
        for (int t = 0; t < 14; ++t)
            *(uint2*)(&Wl[p][wdst[t]]) =
                make_uint2(pk2(wb[t].x, wb[t].y), pk2(wb[t].z, wb[t].w));
        #pragma unroll
        for (int t = 0; t < 4; ++t) if (aok[t]) {
            *(uint2*)(&Al[p][adst[t]])     = make_uint2(ab[t].x, ab[t].y);
            *(uint2*)(&Al[p][adst[t] + 4]) = make_uint2(ab[t].z, ab[t].w);
        }
    };

    f32x4 acc = {0.f, 0.f, 0.f, 0.f};
    LOADS(0); WRITE(0); __syncthreads();
    int p = 0;
    for (int s = 0; s < NSTEP; ++s) {
        if (s + 1 < NSTEP) LOADS(s + 1);    // issue next-stage HBM loads into regs
        #pragma unroll
        for (int m = 0; m < 7; ++m) {       // compute current stage from buf p
            int k = m * 32;
            bf16x8 a = ld_frag(&Al[p][n * LDW + k + quad * 8]);
            bf16x8 b = ld_frag(&Wl[p][(wv * 16 + n) * LDW + k + quad * 8]);
            acc = __builtin_amdgcn_mfma_f32_16x16x32_bf16(a, b, acc, 0, 0, 0);
        }
        if (s + 1 < NSTEP) WRITE(p ^ 1);    // vmcnt wait lands here, after compute
        __syncthreads();
        p ^= 1;
    }
    int j = jt * 32 + wv * 16 + n;
    if (j < TT_) {
        #pragma unroll
        for (int r = 0; r < 4; ++r)
            unsafeAtomicAdd(&xt[(size_t)(quad * 4 + r) * TT_ + j], acc[r]);
    }
}

// ---------------------------------------------------------------- offsets -> unnormalized sample coord ix
// Folds b_time into the dot (xt holds the bias-free sums). 98 waves total -> latency-bound;
// unroll 4 keeps ~4 f32x4 loads per stream in flight.
__global__ __launch_bounds__(256) void k_off(const float* __restrict__ xt,
                                             const float* __restrict__ bt,
                                             const float* __restrict__ Wa,
                                             const float* __restrict__ Wd,
                                             float* __restrict__ wix) {
    int o = blockIdx.x * 256 + threadIdx.x;
    if (o >= 2 * BB * KK) return;                  // 6272
    int which = o / (BB * KK);                     // 0 = a, 1 = d
    int rem = o - which * (BB * KK);
    int b = rem / KK;
    int k = rem - b * KK;
    const f32x4* __restrict__ wr = (const f32x4*)((which ? Wd : Wa) + (size_t)k * TT_);
    const f32x4* __restrict__ xr = (const f32x4*)(xt + (size_t)b * TT_);
    const f32x4* __restrict__ br = (const f32x4*)bt;
    float acc = 0.f;
    #pragma unroll 4
    for (int q = 0; q < TT_ / 4; ++q) {
        f32x4 w = wr[q], x = xr[q], bb = br[q];
        acc += (x.x + bb.x) * w.x + (x.y + bb.y) * w.y
             + (x.z + bb.z) * w.z + (x.w + bb.w) * w.w;
    }
    float off = tanhf(acc) * 2.0f;                 // * RECEPTIVE_FIELD
    float idx = (float)(2 * k + which) + off;      // arange(0,t,2) or arange(1,t+1,2)
    float g = 2.0f * idx / 391.0f - 1.0f;          // normalize_grid, denom = t-1
    float ix = ((g + 1.0f) * 512.0f - 1.0f) * 0.5f; // grid_sample unnormalize, c=512
    wix[o] = ix;
}

// ---------------------------------------------------------------- bilinear gather along channels
__global__ __launch_bounds__(256) void k_sample(const float* __restrict__ x,
                                                const float* __restrict__ wix,
                                                float* __restrict__ out) {
    __shared__ float xr[4][512];
    int b = blockIdx.x, t0 = blockIdx.y * 4;
    int tid = threadIdx.x;
    const float* src = x + ((size_t)b * TT_ + t0) * CC;
    #pragma unroll
    for (int s = 0; s < 2; ++s) {
        int idx = s * 256 + tid;                   // 0..511 float4 slots
        ((f32x4*)xr)[idx] = ((const f32x4*)src)[idx];
    }
    __syncthreads();
    for (int w = tid; w < 2 * 4 * KK; w += 256) {  // 1568 items
        int which = (w >= 4 * KK) ? 1 : 0;
        int rem = w - which * 4 * KK;
        int tl = rem / KK;
        int k = rem - tl * KK;
        float ix = wix[(size_t)which * (BB * KK) + b * KK + k];
        float x0f = floorf(ix);
        float w1 = ix - x0f;
        int c0 = (int)x0f;
        int c1 = c0 + 1;
        c0 = min(max(c0, 0), CC - 1);
        c1 = min(max(c1, 0), CC - 1);
        float v0 = xr[tl][c0], v1 = xr[tl][c1];
        out[(size_t)which * OUT_HALF + ((size_t)(b * TT_) + t0 + tl) * KK + k] =
            v0 * (1.0f - w1) + v1 * w1;
    }
}

extern "C" void kernel_launch(void* const* d_in, const int* in_sizes, int n_in,
                              void* d_out, int out_size, void* d_ws, size_t ws_size,
                              hipStream_t stream) {
    const float* x_in   = (const float*)d_in[0];
    const float* W_dim  = (const float*)d_in[1];
    const float* b_dim  = (const float*)d_in[2];
    const float* W_time = (const float*)d_in[3];
    const float* b_time = (const float*)d_in[4];
    const float* W_offa = (const float*)d_in[5];
    const float* W_offd = (const float*)d_in[6];
    float* out = (float*)d_out;
    float* ws  = (float*)d_ws;

    // ws layout (float units):
    unsigned short* att_b = (unsigned short*)ws;             // 16*153664 bf16
    unsigned short* xi_b  = (unsigned short*)(ws + 1229312); // 6272*64 bf16 (region kept fl-sized)
    float*          xt    = ws + 1630720;                    // 6,272 fl (zeroed by k_xi)
    float*          wix   = ws + 1636992;                    // 6,272 fl
    // total ~6.6 MB

    k_xi<<<98, 256, 0, stream>>>(x_in, W_dim, b_dim, xi_b, xt);
    k_att<<<dim3(BB, 7), 256, 0, stream>>>(xi_b, att_b);
    k_xt<<<dim3(NC2, NJT), 128, 0, stream>>>(W_time, att_b, xt);
    k_off<<<25, 256, 0, stream>>>(xt, b_time, W_offa, W_offd, wix);
    k_sample<<<dim3(BB, TT_ / 4), 256, 0, stream>>>(x_in, wix, out);
}